// Round 2
// baseline (460.616 us; speedup 1.0000x reference)
//
#include <hip/hip_runtime.h>

// MeshVerticalLayer: for output col j (r=rperm[j], p=pair[r]):
//   out[0,b,j] = x0[lr]*d0[r] - x1[lr]*d1[r] + x0[lp]*f0[p] - x1[lp]*f1[p]
//   out[1,b,j] = x0[lr]*d1[r] + x1[lr]*d0[r] + x0[lp]*f1[p] + x1[lp]*f0[p]
// with lr=lperm[r], lp=lperm[p]. x:[2,B,N] fp32, N=1024, B=32768.
// HBM-bound: 256 MB in + 256 MB out -> ~81 us floor at 6.3 TB/s.
//
// Structure: NO __syncthreads. Each wave owns a private 8 KB LDS slice,
// stages its own batch's two channel rows (coalesced dwordx4), then does
// scalar LDS gathers. Same-wave LDS ops are in-order in the LDS pipe, so
// cross-lane RAW within the wave needs only a compiler fence (wave_barrier).

#define NCOLS 1024
#define TPB   256            // 4 waves per block
#define WPB   4
#define WB    8              // batches per wave

__global__ __launch_bounds__(TPB) void mesh_kernel(
    const float* __restrict__ x,      // [2,B,N]
    const float* __restrict__ diag,   // [2,N]
    const float* __restrict__ offd,   // [2,N]
    const int*   __restrict__ pair,   // [N]
    const int*   __restrict__ lperm,  // [N]
    const int*   __restrict__ rperm,  // [N]
    float* __restrict__ out,          // [2,B,N]
    int B)
{
    // wave-private staging: [wave][x0 row (1024) | x1 row (1024)]
    __shared__ __align__(16) float smem[WPB][2 * NCOLS];

    const int t    = threadIdx.x;
    const int lane = t & 63;
    const int wave = t >> 6;
    float* sb = smem[wave];

    // ---- per-lane column table (amortized over WB batches) ----
    // lane handles cols j = 4*lane + 256*g + q  (g,q in 0..3) -> 4 contiguous
    // cols per group g => float4 output stores, perfectly coalesced.
    int   addr[16];                       // (lr*4) | (lp*4 << 16)  LDS byte addrs
    float d0[16], d1[16], f0[16], f1[16];
#pragma unroll
    for (int g = 0; g < 4; ++g) {
#pragma unroll
        for (int q = 0; q < 4; ++q) {
            const int i = g * 4 + q;
            const int j = 4 * lane + 256 * g + q;
            const int r = rperm[j];
            const int p = pair[r];
            addr[i] = (lperm[r] << 2) | (lperm[p] << 18);
            d0[i] = diag[r];
            d1[i] = diag[NCOLS + r];
            f0[i] = offd[p];
            f1[i] = offd[NCOLS + p];
        }
    }

    const long long BN = (long long)B * NCOLS;
    const int w  = blockIdx.x * WPB + wave;   // global wave id
    const int b0 = w * WB;

    for (int it = 0; it < WB; ++it) {
        const int b = b0 + it;
        if (b >= B) break;

        // ---- stage both channel rows into this wave's LDS slice ----
        const float4* r0 = (const float4*)(x + (long long)b * NCOLS);
        const float4* r1 = (const float4*)(x + BN + (long long)b * NCOLS);
        float4* s0 = (float4*)sb;
        float4* s1 = (float4*)(sb + NCOLS);
#pragma unroll
        for (int u = 0; u < 4; ++u) {           // 256 float4 per row / 64 lanes
            s0[lane + 64 * u] = r0[lane + 64 * u];
            s1[lane + 64 * u] = r1[lane + 64 * u];
        }
        __builtin_amdgcn_wave_barrier();   // compiler fence: writes before reads

        // ---- gather + complex MAC + coalesced float4 stores ----
        const char* sc = (const char*)sb;
        float* ob0 = out + (long long)b * NCOLS;
        float* ob1 = out + BN + (long long)b * NCOLS;
#pragma unroll
        for (int g = 0; g < 4; ++g) {
            float4 o0, o1;
            float* o0p = &o0.x;
            float* o1p = &o1.x;
#pragma unroll
            for (int q = 0; q < 4; ++q) {
                const int i = g * 4 + q;
                const int alr = addr[i] & 0xFFFF;          // lr*4
                const int alp = (addr[i] >> 16) & 0xFFFF;  // lp*4
                const float a0 = *(const float*)(sc + alr);
                const float a1 = *(const float*)(sc + alr + 4 * NCOLS);
                const float e0 = *(const float*)(sc + alp);
                const float e1 = *(const float*)(sc + alp + 4 * NCOLS);
                o0p[q] = a0 * d0[i] - a1 * d1[i] + e0 * f0[i] - e1 * f1[i];
                o1p[q] = a0 * d1[i] + a1 * d0[i] + e0 * f1[i] + e1 * f0[i];
            }
            ((float4*)(ob0 + 256 * g))[lane] = o0;
            ((float4*)(ob1 + 256 * g))[lane] = o1;
        }
        __builtin_amdgcn_wave_barrier();   // fence: reads before next iter writes
    }
}

extern "C" void kernel_launch(void* const* d_in, const int* in_sizes, int n_in,
                              void* d_out, int out_size, void* d_ws, size_t ws_size,
                              hipStream_t stream) {
    const float* x     = (const float*)d_in[0];
    const float* diag  = (const float*)d_in[1];
    const float* offd  = (const float*)d_in[2];
    const int*   pair  = (const int*)d_in[3];
    const int*   lperm = (const int*)d_in[4];
    const int*   rperm = (const int*)d_in[5];
    float* out = (float*)d_out;

    const int N = in_sizes[1] / 2;          // 1024
    const int B = in_sizes[0] / (2 * N);    // 32768
    (void)N;

    const int waves  = (B + WB - 1) / WB;   // 4096
    const int blocks = (waves + WPB - 1) / WPB;  // 1024
    mesh_kernel<<<dim3(blocks), dim3(TPB), 0, stream>>>(
        x, diag, offd, pair, lperm, rperm, out, B);
}